// Round 5
// baseline (158.555 us; speedup 1.0000x reference)
//
#include <hip/hip_runtime.h>
#include <hip/hip_bf16.h>
#include <hip/hip_fp16.h>
#include <math.h>

// Problem constants: B=1, N=512, FN=8, FE=1, E=32, D0=14, 8 frames.
#define NN 512

typedef _Float16 f16x8 __attribute__((ext_vector_type(8)));
typedef float    f32x4 __attribute__((ext_vector_type(4)));

// ---------------------------------------------------------------------------
// Covariance reduction (f64) + 3x3 Jacobi eigh (f32). Redundant per block.
// Result in sFR[12]: [0..2]=center, [3+r*3+c]=V[r][c], eigen-cols ascending.
// ---------------------------------------------------------------------------
__device__ __forceinline__ void compute_frame(const float* __restrict__ x,
                                              float* __restrict__ sFR,
                                              double (*red)[9]) {
    const int t = threadIdx.x;
    double s[9] = {0,0,0,0,0,0,0,0,0};
    for (int n = t; n < NN; n += 256) {
        double X = x[n*3+0], Y = x[n*3+1], Z = x[n*3+2];
        s[0]+=X; s[1]+=Y; s[2]+=Z;
        s[3]+=X*X; s[4]+=X*Y; s[5]+=X*Z; s[6]+=Y*Y; s[7]+=Y*Z; s[8]+=Z*Z;
    }
    #pragma unroll
    for (int m = 1; m < 64; m <<= 1) {
        #pragma unroll
        for (int q = 0; q < 9; ++q) s[q] += __shfl_xor(s[q], m);
    }
    const int wave = t >> 6, lane = t & 63;
    if (lane == 0) {
        #pragma unroll
        for (int q = 0; q < 9; ++q) red[wave][q] = s[q];
    }
    __syncthreads();
    if (t == 0) {
        double S[9];
        #pragma unroll
        for (int q = 0; q < 9; ++q) S[q] = red[0][q]+red[1][q]+red[2][q]+red[3][q];
        double cx = S[0]/512.0, cy = S[1]/512.0, cz = S[2]/512.0;
        float A[3][3], V[3][3] = {{1,0,0},{0,1,0},{0,0,1}};
        A[0][0]=(float)(S[3]-512.0*cx*cx); A[0][1]=(float)(S[4]-512.0*cx*cy);
        A[0][2]=(float)(S[5]-512.0*cx*cz); A[1][1]=(float)(S[6]-512.0*cy*cy);
        A[1][2]=(float)(S[7]-512.0*cy*cz); A[2][2]=(float)(S[8]-512.0*cz*cz);
        A[1][0]=A[0][1]; A[2][0]=A[0][2]; A[2][1]=A[1][2];
        for (int sweep = 0; sweep < 8; ++sweep) {
            float off = fabsf(A[0][1]) + fabsf(A[0][2]) + fabsf(A[1][2]);
            float dia = fabsf(A[0][0]) + fabsf(A[1][1]) + fabsf(A[2][2]);
            if (off < 1e-7f * (dia + 1e-30f)) break;
            for (int p = 0; p < 3; ++p) for (int q = p+1; q < 3; ++q) {
                float apq = A[p][q];
                if (fabsf(apq) < 1e-30f) continue;
                float tau = (A[q][q] - A[p][p]) / (2.0f * apq);
                float tt = (tau >= 0.f ? 1.0f : -1.0f) / (fabsf(tau) + sqrtf(1.0f + tau*tau));
                float cc = 1.0f / sqrtf(1.0f + tt*tt), ss = tt * cc;
                A[p][p] = A[p][p] - tt * apq;
                A[q][q] = A[q][q] + tt * apq;
                A[p][q] = 0.0f; A[q][p] = 0.0f;
                for (int k = 0; k < 3; ++k) if (k != p && k != q) {
                    float akp = A[k][p], akq = A[k][q];
                    A[k][p] = cc*akp - ss*akq; A[p][k] = A[k][p];
                    A[k][q] = ss*akp + cc*akq; A[q][k] = A[k][q];
                }
                for (int k = 0; k < 3; ++k) {
                    float vkp = V[k][p], vkq = V[k][q];
                    V[k][p] = cc*vkp - ss*vkq;
                    V[k][q] = ss*vkp + cc*vkq;
                }
            }
        }
        float ev[3] = {A[0][0], A[1][1], A[2][2]};
        int idx[3] = {0,1,2};
        for (int a = 0; a < 2; ++a) for (int b = a+1; b < 3; ++b)
            if (ev[idx[b]] < ev[idx[a]]) { int tmp = idx[a]; idx[a] = idx[b]; idx[b] = tmp; }
        sFR[0] = (float)cx; sFR[1] = (float)cy; sFR[2] = (float)cz;
        for (int r = 0; r < 3; ++r)
            for (int c = 0; c < 3; ++c)
                sFR[3 + r*3 + c] = V[r][idx[c]];
    }
    __syncthreads();
}

// ---------------------------------------------------------------------------
// K1: frame + h0 + layer-0 pre-projections + weight convert + edge passthrough.
// 512 blocks x 256 thr. PJ written FRAGMENT-MAJOR (PJF):
//   PJF[((o*32 + (j>>4))*64 + ((j&15)|((c>>3)<<4)))*8 + (c&7)]
// ---------------------------------------------------------------------------
__global__ void __launch_bounds__(256) pre0_kernel(
    const float* __restrict__ x, const float* __restrict__ v,
    const float* __restrict__ nf,
    const float* __restrict__ e0w1, const float* __restrict__ e0b1,
    const float* __restrict__ e0w2, const float* __restrict__ e1w1,
    const float* __restrict__ e1w2,
    const float* __restrict__ edge,
    float* __restrict__ FRg, float* __restrict__ H0,
    _Float16* __restrict__ PJF, _Float16* __restrict__ PIH,
    _Float16* __restrict__ WEH0, _Float16* __restrict__ WEH1,
    _Float16* __restrict__ W2F0, _Float16* __restrict__ W2F1,
    float* __restrict__ out_edge)
{
    __shared__ double red[4][9];
    __shared__ float sFR[12];
    const int t = threadIdx.x;
    const int b = blockIdx.x;

    // Passthrough first so the stores fly under the Jacobi latency.
    ((float2*)out_edge)[b * 256 + t] = ((const float2*)edge)[b * 256 + t];

    compute_frame(x, sFR, red);

    const int lane = t & 63, wv = t >> 6;
    if (b == 0) {
        if (t < 12) FRg[t] = sFR[t];
        const int l15 = lane & 15, kb = (lane >> 4) * 8;
        if (wv == 1) {
            #pragma unroll
            for (int e = 0; e < 8; ++e) {
                W2F0[lane*16 + e]     = (_Float16)e0w2[(kb+e)*32 + l15];
                W2F0[lane*16 + 8 + e] = (_Float16)e0w2[(kb+e)*32 + l15 + 16];
            }
        } else if (wv == 2) {
            #pragma unroll
            for (int e = 0; e < 8; ++e) {
                W2F1[lane*16 + e]     = (_Float16)e1w2[(kb+e)*32 + l15];
                W2F1[lane*16 + 8 + e] = (_Float16)e1w2[(kb+e)*32 + l15 + 16];
            }
        } else if (wv == 3 && lane < 32) {
            WEH0[lane] = (_Float16)e0w1[lane];
            WEH1[lane] = (_Float16)e1w1[lane];
        }
    }

    const int c = t & 31;
    const int row = b * 8 + (t >> 5);
    const int o = row >> 9, j = row & 511;
    float hrow[14];
    float xc0 = x[j*3+0] - sFR[0], xc1 = x[j*3+1] - sFR[1], xc2 = x[j*3+2] - sFR[2];
    float v0 = v[j*3+0], v1 = v[j*3+1], v2 = v[j*3+2];
    #pragma unroll
    for (int i = 0; i < 3; ++i) {
        float sgn = ((o >> (2 - i)) & 1) ? -1.f : 1.f;
        float px = sFR[3 + 0*3 + i]*xc0 + sFR[3 + 1*3 + i]*xc1 + sFR[3 + 2*3 + i]*xc2;
        float pv = sFR[3 + 0*3 + i]*v0  + sFR[3 + 1*3 + i]*v1  + sFR[3 + 2*3 + i]*v2;
        hrow[i]     = sgn * px;
        hrow[3 + i] = sgn * pv;
    }
    #pragma unroll
    for (int k = 0; k < 8; ++k) hrow[6 + k] = nf[j*8 + k];
    if (c < 14) H0[row * 14 + c] = hrow[c];
    float pj = 0.f, pi = e0b1[c];
    #pragma unroll
    for (int k = 0; k < 14; ++k) {
        pj = fmaf(hrow[k], e0w1[(1 + k) * 32 + c], pj);
        pi = fmaf(hrow[k], e0w1[(15 + k) * 32 + c], pi);
    }
    PIH[row * 32 + c] = (_Float16)pi;
    const int fl = (j & 15) | ((c >> 3) << 4);
    PJF[(((o << 5) + (j >> 4)) * 64 + fl) * 8 + (c & 7)] = (_Float16)pj;
}

// ---------------------------------------------------------------------------
// K2: ONE FULL ROW (o,i) PER WAVE. 1024 blocks x 4 waves = 4096 independent
// waves, exactly resident at 4 blocks/CU (__launch_bounds__(256,4)), so each
// SIMD interleaves 4 independent VALU/MFMA streams — no LDS, no syncthreads,
// no early return, no inter-wave coupling of any kind. Quad-reduced agg is
// realigned with pure shuffles; node-MLP tail half-split across lane halves.
// NEXT fuses the next layer's pre-projection.
// ---------------------------------------------------------------------------
template<int D, bool NEXT>
__global__ void __launch_bounds__(256, 4) edge_kernel(
    const _Float16* __restrict__ PJF,   // [8][32][64][8] f16 fragment-major
    const _Float16* __restrict__ PIH,   // [4096][32] f16 (includes +eb1)
    const _Float16* __restrict__ WEH,   // [32] f16
    const _Float16* __restrict__ W2F,   // [64][16] f16 B-fragments
    const float* __restrict__ edge,     // [512][512]
    const float* __restrict__ h,        // [4096][D] f32
    const float* __restrict__ eb2,
    const float* __restrict__ nw1,      // [D+32][32]
    const float* __restrict__ nb1,
    const float* __restrict__ nw2,      // [32][32]
    const float* __restrict__ nb2,
    float* __restrict__ hout,           // [4096][32] f32
    const float* __restrict__ ew1n,
    const float* __restrict__ eb1n,
    _Float16* __restrict__ PJFn,
    _Float16* __restrict__ PIn)
{
    const int lane = threadIdx.x & 63;
    const int w = (blockIdx.x << 2) | (threadIdx.x >> 6);  // global wave 0..4095
    const int o = w >> 9;
    const int i = w & 511;
    const int row = w;                  // (o<<9)|i == w
    const int l15 = lane & 15;
    const int kbase = (lane >> 4) * 8;

    const f16x8 pi8 = *(const f16x8*)(PIH + row * 32 + kbase);
    const f16x8 we8 = *(const f16x8*)(WEH + kbase);
    const f16x8 bf0 = *(const f16x8*)(W2F + lane * 16);
    const f16x8 bf1 = *(const f16x8*)(W2F + lane * 16 + 8);
    const float b2v0 = eb2[l15], b2v1 = eb2[l15 + 16];
    const f16x8 z8 = {0,0,0,0,0,0,0,0};
    float agg0 = 0.f, agg1 = 0.f;

    const float* edge_i = edge + (i << 9);
    const _Float16* pjf_o = PJF + (size_t)o * 16384;   // 32 tiles * 512

    #pragma unroll 8
    for (int tile = 0; tile < 32; ++tile) {
        const f16x8 pj8 = *(const f16x8*)(pjf_o + (tile * 64 + lane) * 8);
        const _Float16 eh = (_Float16)edge_i[tile * 16 + l15];
        const f16x8 e8 = {eh, eh, eh, eh, eh, eh, eh, eh};
        f16x8 m = e8 * we8 + (pj8 + pi8);          // v_pk_fma_f16 + v_pk_add_f16
        m = __builtin_elementwise_max(m, z8);      // v_pk_max_f16
        f32x4 c0 = {0.f, 0.f, 0.f, 0.f};
        c0 = __builtin_amdgcn_mfma_f32_16x16x32_f16(m, bf0, c0, 0, 0, 0);
        #pragma unroll
        for (int r = 0; r < 4; ++r) agg0 += fmaxf(c0[r] + b2v0, 0.f);
        f32x4 c1 = {0.f, 0.f, 0.f, 0.f};
        c1 = __builtin_amdgcn_mfma_f32_16x16x32_f16(m, bf1, c1, 0, 0, 0);
        #pragma unroll
        for (int r = 0; r < 4; ++r) agg1 += fmaxf(c1[r] + b2v1, 0.f);
    }
    // Quad partials: lanes l, l^16, l^32, l^48 share C-col l15. After these,
    // realign so every lane holds its channel (lane&31) via a pure select.
    agg0 += __shfl_xor(agg0, 16); agg0 += __shfl_xor(agg0, 32);
    agg1 += __shfl_xor(agg1, 16); agg1 += __shfl_xor(agg1, 32);
    const float red2 = (lane & 16) ? agg1 : agg0;

    // Node MLP, half-split across the two 32-lane halves.
    const int c2 = lane & 31;
    const int hf = lane >> 5;
    const int kb = hf << 4;
    const float* hr = h + row * D;            // wave-uniform base
    constexpr int DH = D / 2;
    float acc = hf ? 0.f : nb1[c2];
    #pragma unroll
    for (int kk = 0; kk < DH; ++kk) {
        const int k = hf * DH + kk;
        acc = fmaf(hr[k], nw1[k * 32 + c2], acc);
    }
    #pragma unroll
    for (int kk = 0; kk < 16; ++kk) {
        const int k = kb + kk;
        acc = fmaf(__shfl(red2, k, 32), nw1[(D + k) * 32 + c2], acc);
    }
    acc += __shfl_xor(acc, 32);
    const float dn = fmaxf(acc, 0.f);
    float outv = hf ? 0.f : nb2[c2];
    #pragma unroll
    for (int kk = 0; kk < 16; ++kk) {
        const int k = kb + kk;
        outv = fmaf(__shfl(dn, k, 32), nw2[k * 32 + c2], outv);
    }
    outv += __shfl_xor(outv, 32);
    if (lane < 32) hout[row * 32 + c2] = outv;

    if (NEXT) {
        float pj1 = 0.f, pi1 = hf ? 0.f : eb1n[c2];
        #pragma unroll
        for (int kk = 0; kk < 16; ++kk) {
            const int k = kb + kk;
            const float hk = __shfl(outv, k, 32);
            pj1 = fmaf(hk, ew1n[(1 + k) * 32 + c2], pj1);
            pi1 = fmaf(hk, ew1n[(33 + k) * 32 + c2], pi1);
        }
        pj1 += __shfl_xor(pj1, 32);
        pi1 += __shfl_xor(pi1, 32);
        if (lane < 32) {
            PIn[row * 32 + c2] = (_Float16)pi1;
            const int fl = (i & 15) | ((c2 >> 3) << 4);
            PJFn[(((o << 5) + (i >> 4)) * 64 + fl) * 8 + (c2 & 7)] = (_Float16)pj1;
        }
    }
}

// ---------------------------------------------------------------------------
// K3: fused decoder + h_mean + coef MLP + invert_frame. One block per node n.
// ---------------------------------------------------------------------------
__global__ void __launch_bounds__(256) decfinal_kernel(
    const float* __restrict__ h2,
    const float* __restrict__ w1, const float* __restrict__ b1,
    const float* __restrict__ w2,   // [32][6]
    const float* __restrict__ b2,
    const float* __restrict__ x, const float* __restrict__ v,
    const float* __restrict__ FR,
    const float* __restrict__ vw1, const float* __restrict__ vb1,
    const float* __restrict__ vw2, const float* __restrict__ vb2,
    float* __restrict__ out_hmean, float* __restrict__ out_x,
    float* __restrict__ out_v)
{
    const int n = blockIdx.x;                 // 0..511
    const int t = threadIdx.x;
    const int wv = t >> 6, lane = t & 63;
    const int c = lane & 31;
    __shared__ float sSo[8][6];

    #pragma unroll
    for (int q = 0; q < 2; ++q) {
        const int o = (wv << 1) | q;
        const int row = (o << 9) | n;
        float rh = fmaxf(h2[row * 32 + c], 0.f);
        float acc = b1[c];
        #pragma unroll
        for (int k = 0; k < 32; ++k)
            acc = fmaf(__shfl(rh, k, 32), w1[k * 32 + c], acc);
        float s = fmaxf(acc, 0.f);
        #pragma unroll
        for (int m = 0; m < 6; ++m) {
            float p = s * w2[c * 6 + m];
            p += __shfl_xor(p, 1); p += __shfl_xor(p, 2); p += __shfl_xor(p, 4);
            p += __shfl_xor(p, 8); p += __shfl_xor(p, 16);
            if (lane == 0) sSo[o][m] = p + b2[m];
        }
    }
    __syncthreads();
    if (wv) return;

    float hm = 0.f;
    #pragma unroll
    for (int o = 0; o < 8; ++o) hm += h2[((o << 9) | n) * 32 + c];
    hm *= 0.125f;
    if (lane < 32) out_hmean[n * 32 + c] = hm;
    float rh = fmaxf(hm, 0.f);
    float acc = vb1[c];
    #pragma unroll
    for (int k = 0; k < 32; ++k)
        acc = fmaf(__shfl(rh, k, 32), vw1[k * 32 + c], acc);
    float t1 = fmaxf(acc, 0.f);
    float p = t1 * vw2[c];
    p += __shfl_xor(p, 1); p += __shfl_xor(p, 2); p += __shfl_xor(p, 4);
    p += __shfl_xor(p, 8); p += __shfl_xor(p, 16);
    float coef = p + vb2[0];
    if (lane < 3) {
        int i = lane;
        float dx = 0.f, dv = 0.f;
        #pragma unroll
        for (int o = 0; o < 8; ++o) {
            #pragma unroll
            for (int j = 0; j < 3; ++j) {
                float sgn = ((o >> (2 - j)) & 1) ? -1.f : 1.f;
                float f = sgn * FR[3 + i * 3 + j];
                dx = fmaf(f, sSo[o][j], dx);
                dv = fmaf(f, sSo[o][3 + j], dv);
            }
        }
        dx *= 0.125f; dv *= 0.125f;
        float vout = v[n * 3 + i] + dv;
        out_v[n * 3 + i] = vout;
        out_x[n * 3 + i] = x[n * 3 + i] + vout * coef + dx;
    }
}

// ---------------------------------------------------------------------------
extern "C" void kernel_launch(void* const* d_in, const int* in_sizes, int n_in,
                              void* d_out, int out_size, void* d_ws, size_t ws_size,
                              hipStream_t stream) {
    const float* node_feat = (const float*)d_in[0];
    const float* edge      = (const float*)d_in[1];
    const float* x         = (const float*)d_in[2];
    const float* v         = (const float*)d_in[3];
    const float* e0_w1 = (const float*)d_in[4];
    const float* e0_b1 = (const float*)d_in[5];
    const float* e0_w2 = (const float*)d_in[6];
    const float* e0_b2 = (const float*)d_in[7];
    const float* n0_w1 = (const float*)d_in[8];
    const float* n0_b1 = (const float*)d_in[9];
    const float* n0_w2 = (const float*)d_in[10];
    const float* n0_b2 = (const float*)d_in[11];
    const float* e1_w1 = (const float*)d_in[12];
    const float* e1_b1 = (const float*)d_in[13];
    const float* e1_w2 = (const float*)d_in[14];
    const float* e1_b2 = (const float*)d_in[15];
    const float* n1_w1 = (const float*)d_in[16];
    const float* n1_b1 = (const float*)d_in[17];
    const float* n1_w2 = (const float*)d_in[18];
    const float* n1_b2 = (const float*)d_in[19];
    const float* dec_w1 = (const float*)d_in[20];
    const float* dec_b1 = (const float*)d_in[21];
    const float* dec_w2 = (const float*)d_in[22];
    const float* dec_b2 = (const float*)d_in[23];
    const float* vc_w1 = (const float*)d_in[24];
    const float* vc_b1 = (const float*)d_in[25];
    const float* vc_w2 = (const float*)d_in[26];
    const float* vc_b2 = (const float*)d_in[27];

    char* wsb = (char*)d_ws;
    float* out = (float*)d_out;

    float*    FR   = (float*)wsb;                            // 12 f32
    float*    H0   = (float*)(wsb + 256);                    // 57344 f32
    float*    HA   = (float*)(wsb + 256 + 229376);           // 131072 f32
    float*    HB   = (float*)(wsb + 256 + 229376 + 524288);  // 131072 f32
    char*     p    = wsb + 256 + 229376 + 524288 + 524288;
    _Float16* PJF0 = (_Float16*)p;            p += 262144;   // 131072 f16
    _Float16* PIH0 = (_Float16*)p;            p += 262144;
    _Float16* PJF1 = (_Float16*)p;            p += 262144;
    _Float16* PIH1 = (_Float16*)p;            p += 262144;
    _Float16* WEH0 = (_Float16*)p;            p += 256;
    _Float16* WEH1 = (_Float16*)p;            p += 256;
    _Float16* W2F0 = (_Float16*)p;            p += 2048;
    _Float16* W2F1 = (_Float16*)p;            p += 2048;

    // K1: frame + h0 + layer-0 pre + weight convert + edge passthrough
    pre0_kernel<<<512, 256, 0, stream>>>(x, v, node_feat,
                                         e0_w1, e0_b1, e0_w2, e1_w1, e1_w2,
                                         edge, FR, H0, PJF0, PIH0,
                                         WEH0, WEH1, W2F0, W2F1, out + 16384);
    // K2: layer 0 (D=14), one row per wave, 4096 waves fully resident
    edge_kernel<14, true><<<1024, 256, 0, stream>>>(
        PJF0, PIH0, WEH0, W2F0, edge, H0, e0_b2, n0_w1, n0_b1, n0_w2, n0_b2,
        HA, e1_w1, e1_b1, PJF1, PIH1);
    // K2': layer 1 (D=32)
    edge_kernel<32, false><<<1024, 256, 0, stream>>>(
        PJF1, PIH1, WEH1, W2F1, edge, HA, e1_b2, n1_w1, n1_b1, n1_w2, n1_b2,
        HB, nullptr, nullptr, nullptr, nullptr);
    // K3: decoder + outputs
    decfinal_kernel<<<512, 256, 0, stream>>>(HB, dec_w1, dec_b1, dec_w2, dec_b2,
                                             x, v, FR, vc_w1, vc_b1, vc_w2, vc_b2,
                                             out, out + 278528, out + 280064);
}

// Round 6
// 155.245 us; speedup vs baseline: 1.0213x; 1.0213x over previous
//
#include <hip/hip_runtime.h>
#include <hip/hip_bf16.h>
#include <hip/hip_fp16.h>
#include <math.h>

// Problem constants: B=1, N=512, FN=8, FE=1, E=32, D0=14, 8 frames.
#define NN 512

typedef _Float16 f16x8 __attribute__((ext_vector_type(8)));
typedef float    f32x4 __attribute__((ext_vector_type(4)));

// ---------------------------------------------------------------------------
// Covariance reduction (f64) + 3x3 Jacobi eigh (f32). Redundant per block.
// Result in sFR[12]: [0..2]=center, [3+r*3+c]=V[r][c], eigen-cols ascending.
// ---------------------------------------------------------------------------
__device__ __forceinline__ void compute_frame(const float* __restrict__ x,
                                              float* __restrict__ sFR,
                                              double (*red)[9]) {
    const int t = threadIdx.x;
    double s[9] = {0,0,0,0,0,0,0,0,0};
    for (int n = t; n < NN; n += 256) {
        double X = x[n*3+0], Y = x[n*3+1], Z = x[n*3+2];
        s[0]+=X; s[1]+=Y; s[2]+=Z;
        s[3]+=X*X; s[4]+=X*Y; s[5]+=X*Z; s[6]+=Y*Y; s[7]+=Y*Z; s[8]+=Z*Z;
    }
    #pragma unroll
    for (int m = 1; m < 64; m <<= 1) {
        #pragma unroll
        for (int q = 0; q < 9; ++q) s[q] += __shfl_xor(s[q], m);
    }
    const int wave = t >> 6, lane = t & 63;
    if (lane == 0) {
        #pragma unroll
        for (int q = 0; q < 9; ++q) red[wave][q] = s[q];
    }
    __syncthreads();
    if (t == 0) {
        double S[9];
        #pragma unroll
        for (int q = 0; q < 9; ++q) S[q] = red[0][q]+red[1][q]+red[2][q]+red[3][q];
        double cx = S[0]/512.0, cy = S[1]/512.0, cz = S[2]/512.0;
        float A[3][3], V[3][3] = {{1,0,0},{0,1,0},{0,0,1}};
        A[0][0]=(float)(S[3]-512.0*cx*cx); A[0][1]=(float)(S[4]-512.0*cx*cy);
        A[0][2]=(float)(S[5]-512.0*cx*cz); A[1][1]=(float)(S[6]-512.0*cy*cy);
        A[1][2]=(float)(S[7]-512.0*cy*cz); A[2][2]=(float)(S[8]-512.0*cz*cz);
        A[1][0]=A[0][1]; A[2][0]=A[0][2]; A[2][1]=A[1][2];
        for (int sweep = 0; sweep < 8; ++sweep) {
            float off = fabsf(A[0][1]) + fabsf(A[0][2]) + fabsf(A[1][2]);
            float dia = fabsf(A[0][0]) + fabsf(A[1][1]) + fabsf(A[2][2]);
            if (off < 1e-7f * (dia + 1e-30f)) break;
            for (int p = 0; p < 3; ++p) for (int q = p+1; q < 3; ++q) {
                float apq = A[p][q];
                if (fabsf(apq) < 1e-30f) continue;
                float tau = (A[q][q] - A[p][p]) / (2.0f * apq);
                float tt = (tau >= 0.f ? 1.0f : -1.0f) / (fabsf(tau) + sqrtf(1.0f + tau*tau));
                float cc = 1.0f / sqrtf(1.0f + tt*tt), ss = tt * cc;
                A[p][p] = A[p][p] - tt * apq;
                A[q][q] = A[q][q] + tt * apq;
                A[p][q] = 0.0f; A[q][p] = 0.0f;
                for (int k = 0; k < 3; ++k) if (k != p && k != q) {
                    float akp = A[k][p], akq = A[k][q];
                    A[k][p] = cc*akp - ss*akq; A[p][k] = A[k][p];
                    A[k][q] = ss*akp + cc*akq; A[q][k] = A[k][q];
                }
                for (int k = 0; k < 3; ++k) {
                    float vkp = V[k][p], vkq = V[k][q];
                    V[k][p] = cc*vkp - ss*vkq;
                    V[k][q] = ss*vkp + cc*vkq;
                }
            }
        }
        float ev[3] = {A[0][0], A[1][1], A[2][2]};
        int idx[3] = {0,1,2};
        for (int a = 0; a < 2; ++a) for (int b = a+1; b < 3; ++b)
            if (ev[idx[b]] < ev[idx[a]]) { int tmp = idx[a]; idx[a] = idx[b]; idx[b] = tmp; }
        sFR[0] = (float)cx; sFR[1] = (float)cy; sFR[2] = (float)cz;
        for (int r = 0; r < 3; ++r)
            for (int c = 0; c < 3; ++c)
                sFR[3 + r*3 + c] = V[r][idx[c]];
    }
    __syncthreads();
}

// ---------------------------------------------------------------------------
// K1: frame + h0 + layer-0 pre-projections + weight convert + edge passthrough.
// 512 blocks x 256 thr. PJ written FRAGMENT-MAJOR (PJF):
//   PJF[((o*32 + (j>>4))*64 + ((j&15)|((c>>3)<<4)))*8 + (c&7)]
// ---------------------------------------------------------------------------
__global__ void __launch_bounds__(256) pre0_kernel(
    const float* __restrict__ x, const float* __restrict__ v,
    const float* __restrict__ nf,
    const float* __restrict__ e0w1, const float* __restrict__ e0b1,
    const float* __restrict__ e0w2, const float* __restrict__ e1w1,
    const float* __restrict__ e1w2,
    const float* __restrict__ edge,
    float* __restrict__ FRg, float* __restrict__ H0,
    _Float16* __restrict__ PJF, _Float16* __restrict__ PIH,
    _Float16* __restrict__ WEH0, _Float16* __restrict__ WEH1,
    _Float16* __restrict__ W2F0, _Float16* __restrict__ W2F1,
    float* __restrict__ out_edge)
{
    __shared__ double red[4][9];
    __shared__ float sFR[12];
    const int t = threadIdx.x;
    const int b = blockIdx.x;

    // Passthrough first so the stores fly under the Jacobi latency.
    ((float2*)out_edge)[b * 256 + t] = ((const float2*)edge)[b * 256 + t];

    compute_frame(x, sFR, red);

    const int lane = t & 63, wv = t >> 6;
    if (b == 0) {
        if (t < 12) FRg[t] = sFR[t];
        const int l15 = lane & 15, kb = (lane >> 4) * 8;
        if (wv == 1) {
            #pragma unroll
            for (int e = 0; e < 8; ++e) {
                W2F0[lane*16 + e]     = (_Float16)e0w2[(kb+e)*32 + l15];
                W2F0[lane*16 + 8 + e] = (_Float16)e0w2[(kb+e)*32 + l15 + 16];
            }
        } else if (wv == 2) {
            #pragma unroll
            for (int e = 0; e < 8; ++e) {
                W2F1[lane*16 + e]     = (_Float16)e1w2[(kb+e)*32 + l15];
                W2F1[lane*16 + 8 + e] = (_Float16)e1w2[(kb+e)*32 + l15 + 16];
            }
        } else if (wv == 3 && lane < 32) {
            WEH0[lane] = (_Float16)e0w1[lane];
            WEH1[lane] = (_Float16)e1w1[lane];
        }
    }

    const int c = t & 31;
    const int row = b * 8 + (t >> 5);
    const int o = row >> 9, j = row & 511;
    float hrow[14];
    float xc0 = x[j*3+0] - sFR[0], xc1 = x[j*3+1] - sFR[1], xc2 = x[j*3+2] - sFR[2];
    float v0 = v[j*3+0], v1 = v[j*3+1], v2 = v[j*3+2];
    #pragma unroll
    for (int i = 0; i < 3; ++i) {
        float sgn = ((o >> (2 - i)) & 1) ? -1.f : 1.f;
        float px = sFR[3 + 0*3 + i]*xc0 + sFR[3 + 1*3 + i]*xc1 + sFR[3 + 2*3 + i]*xc2;
        float pv = sFR[3 + 0*3 + i]*v0  + sFR[3 + 1*3 + i]*v1  + sFR[3 + 2*3 + i]*v2;
        hrow[i]     = sgn * px;
        hrow[3 + i] = sgn * pv;
    }
    #pragma unroll
    for (int k = 0; k < 8; ++k) hrow[6 + k] = nf[j*8 + k];
    if (c < 14) H0[row * 14 + c] = hrow[c];
    float pj = 0.f, pi = e0b1[c];
    #pragma unroll
    for (int k = 0; k < 14; ++k) {
        pj = fmaf(hrow[k], e0w1[(1 + k) * 32 + c], pj);
        pi = fmaf(hrow[k], e0w1[(15 + k) * 32 + c], pi);
    }
    PIH[row * 32 + c] = (_Float16)pi;
    const int fl = (j & 15) | ((c >> 3) << 4);
    PJF[(((o << 5) + (j >> 4)) * 64 + fl) * 8 + (c & 7)] = (_Float16)pj;
}

// ---------------------------------------------------------------------------
// Node-MLP for one row, in-wave, half-split across the two 32-lane halves.
// red2: lane&31 == channel; shfl(red2,k,32) = agg channel k. Returns outv on
// ALL 64 lanes.
// ---------------------------------------------------------------------------
template<int D>
__device__ __forceinline__ float node_mlp(
    const int row, const float red2,
    const float* __restrict__ h,
    const float* __restrict__ nw1, const float* __restrict__ nb1,
    const float* __restrict__ nw2, const float* __restrict__ nb2)
{
    const int lane = threadIdx.x & 63;
    const int c2 = lane & 31;
    const int hf = lane >> 5;
    const int kb = hf << 4;
    const float* hr = h + row * D;            // wave-uniform base
    constexpr int DH = D / 2;
    float acc = hf ? 0.f : nb1[c2];
    #pragma unroll
    for (int kk = 0; kk < DH; ++kk) {
        const int k = hf * DH + kk;
        acc = fmaf(hr[k], nw1[k * 32 + c2], acc);
    }
    #pragma unroll
    for (int kk = 0; kk < 16; ++kk) {
        const int k = kb + kk;
        acc = fmaf(__shfl(red2, k, 32), nw1[(D + k) * 32 + c2], acc);
    }
    acc += __shfl_xor(acc, 32);
    const float dn = fmaxf(acc, 0.f);
    float outv = hf ? 0.f : nb2[c2];
    #pragma unroll
    for (int kk = 0; kk < 16; ++kk) {
        const int k = kb + kk;
        outv = fmaf(__shfl(dn, k, 32), nw2[k * 32 + c2], outv);
    }
    outv += __shfl_xor(outv, 32);
    return outv;
}

// ---------------------------------------------------------------------------
// Shared edge-MLP loop for a wave's TWO rows (o0,i) and (o0+1,i). The edge
// row load is shared between the two frames. No LDS, no syncthreads: the
// quad-reduced aggregate is realigned purely with shuffles:
//   red = (lane&16) ? agg1 : agg0  gives channel (lane&31) on every lane.
// ---------------------------------------------------------------------------
__device__ __forceinline__ void edge_pair(
    const int o0, const int i,
    const _Float16* __restrict__ PJF, const _Float16* __restrict__ PIH,
    const _Float16* __restrict__ WEH, const _Float16* __restrict__ W2F,
    const float* __restrict__ edge, const float* __restrict__ eb2,
    float& redA, float& redB)
{
    const int lane = threadIdx.x & 63;
    const int l15 = lane & 15;
    const int kbase = (lane >> 4) * 8;
    const int rowA = (o0 << 9) | i;

    const f16x8 piA = *(const f16x8*)(PIH + rowA * 32 + kbase);
    const f16x8 piB = *(const f16x8*)(PIH + (rowA + 512) * 32 + kbase);
    const f16x8 we8 = *(const f16x8*)(WEH + kbase);
    const f16x8 bf0 = *(const f16x8*)(W2F + lane * 16);
    const f16x8 bf1 = *(const f16x8*)(W2F + lane * 16 + 8);
    const float b2v0 = eb2[l15], b2v1 = eb2[l15 + 16];
    const f16x8 z8 = {0,0,0,0,0,0,0,0};
    float aggA0 = 0.f, aggA1 = 0.f, aggB0 = 0.f, aggB1 = 0.f;

    const float* edge_i = edge + (i << 9);
    const _Float16* pjfA = PJF + (size_t)o0 * 16384;   // 32 tiles * 512
    const _Float16* pjfB = pjfA + 16384;

    #pragma unroll 4
    for (int tile = 0; tile < 32; ++tile) {
        const _Float16 eh = (_Float16)edge_i[tile * 16 + l15];
        const f16x8 e8 = {eh, eh, eh, eh, eh, eh, eh, eh};
        const f16x8 pjA = *(const f16x8*)(pjfA + (tile * 64 + lane) * 8);
        const f16x8 pjB = *(const f16x8*)(pjfB + (tile * 64 + lane) * 8);
        f16x8 mA = e8 * we8 + (pjA + piA);
        mA = __builtin_elementwise_max(mA, z8);
        f16x8 mB = e8 * we8 + (pjB + piB);
        mB = __builtin_elementwise_max(mB, z8);
        f32x4 c;
        c = (f32x4){0.f,0.f,0.f,0.f};
        c = __builtin_amdgcn_mfma_f32_16x16x32_f16(mA, bf0, c, 0, 0, 0);
        #pragma unroll
        for (int r = 0; r < 4; ++r) aggA0 += fmaxf(c[r] + b2v0, 0.f);
        c = (f32x4){0.f,0.f,0.f,0.f};
        c = __builtin_amdgcn_mfma_f32_16x16x32_f16(mA, bf1, c, 0, 0, 0);
        #pragma unroll
        for (int r = 0; r < 4; ++r) aggA1 += fmaxf(c[r] + b2v1, 0.f);
        c = (f32x4){0.f,0.f,0.f,0.f};
        c = __builtin_amdgcn_mfma_f32_16x16x32_f16(mB, bf0, c, 0, 0, 0);
        #pragma unroll
        for (int r = 0; r < 4; ++r) aggB0 += fmaxf(c[r] + b2v0, 0.f);
        c = (f32x4){0.f,0.f,0.f,0.f};
        c = __builtin_amdgcn_mfma_f32_16x16x32_f16(mB, bf1, c, 0, 0, 0);
        #pragma unroll
        for (int r = 0; r < 4; ++r) aggB1 += fmaxf(c[r] + b2v1, 0.f);
    }
    // Quad partials: lanes l, l^16, l^32, l^48 share C-col l15.
    aggA0 += __shfl_xor(aggA0, 16); aggA0 += __shfl_xor(aggA0, 32);
    aggA1 += __shfl_xor(aggA1, 16); aggA1 += __shfl_xor(aggA1, 32);
    aggB0 += __shfl_xor(aggB0, 16); aggB0 += __shfl_xor(aggB0, 32);
    aggB1 += __shfl_xor(aggB1, 16); aggB1 += __shfl_xor(aggB1, 32);
    redA = (lane & 16) ? aggA1 : aggA0;
    redB = (lane & 16) ? aggB1 : aggB0;
}

// ---------------------------------------------------------------------------
// K2a: layer 0. Block = node i (512 blocks), wave wv = frames {2wv, 2wv+1}.
// Fuses the layer-1 pre-projection into the tail.
// ---------------------------------------------------------------------------
__global__ void __launch_bounds__(256, 2) edgeA_kernel(
    const _Float16* __restrict__ PJF, const _Float16* __restrict__ PIH,
    const _Float16* __restrict__ WEH, const _Float16* __restrict__ W2F,
    const float* __restrict__ edge, const float* __restrict__ h,   // H0 [4096][14]
    const float* __restrict__ eb2,
    const float* __restrict__ nw1, const float* __restrict__ nb1,
    const float* __restrict__ nw2, const float* __restrict__ nb2,
    float* __restrict__ hout,                                      // HA
    const float* __restrict__ ew1n, const float* __restrict__ eb1n,
    _Float16* __restrict__ PJFn, _Float16* __restrict__ PIn)
{
    const int i = blockIdx.x;
    const int wv = threadIdx.x >> 6, lane = threadIdx.x & 63;
    const int o0 = wv << 1;
    float redA, redB;
    edge_pair(o0, i, PJF, PIH, WEH, W2F, edge, eb2, redA, redB);

    const int c2 = lane & 31;
    const int hf = lane >> 5;
    const int kb = hf << 4;
    const int fl = (i & 15) | ((c2 >> 3) << 4);
    #pragma unroll
    for (int q = 0; q < 2; ++q) {
        const int o = o0 + q;
        const int row = (o << 9) | i;
        const float outv = node_mlp<14>(row, q ? redB : redA, h, nw1, nb1, nw2, nb2);
        if (lane < 32) hout[row * 32 + c2] = outv;
        float pj1 = 0.f, pi1 = hf ? 0.f : eb1n[c2];
        #pragma unroll
        for (int kk = 0; kk < 16; ++kk) {
            const int k = kb + kk;
            const float hk = __shfl(outv, k, 32);
            pj1 = fmaf(hk, ew1n[(1 + k) * 32 + c2], pj1);
            pi1 = fmaf(hk, ew1n[(33 + k) * 32 + c2], pi1);
        }
        pj1 += __shfl_xor(pj1, 32);
        pi1 += __shfl_xor(pi1, 32);
        if (lane < 32) {
            PIn[row * 32 + c2] = (_Float16)pi1;
            PJFn[(((o << 5) + (i >> 4)) * 64 + fl) * 8 + (c2 & 7)] = (_Float16)pj1;
        }
    }
}

// ---------------------------------------------------------------------------
// K2b: layer 1 + fused decoder + h_mean + coef + invert_frame. Block = node i;
// the block holds all 8 frame-rows of node i, so the whole former K3 folds
// into the tail (HB never touches global memory).
// ---------------------------------------------------------------------------
__global__ void __launch_bounds__(256, 2) edgeB_kernel(
    const _Float16* __restrict__ PJF, const _Float16* __restrict__ PIH,
    const _Float16* __restrict__ WEH, const _Float16* __restrict__ W2F,
    const float* __restrict__ edge, const float* __restrict__ h,   // HA [4096][32]
    const float* __restrict__ eb2,
    const float* __restrict__ nw1, const float* __restrict__ nb1,
    const float* __restrict__ nw2, const float* __restrict__ nb2,
    const float* __restrict__ dw1, const float* __restrict__ db1,
    const float* __restrict__ dw2, const float* __restrict__ db2,
    const float* __restrict__ x, const float* __restrict__ v,
    const float* __restrict__ FR,
    const float* __restrict__ vw1, const float* __restrict__ vb1,
    const float* __restrict__ vw2, const float* __restrict__ vb2,
    float* __restrict__ out_hmean, float* __restrict__ out_x,
    float* __restrict__ out_v)
{
    const int i = blockIdx.x;                 // node n
    const int wv = threadIdx.x >> 6, lane = threadIdx.x & 63;
    const int o0 = wv << 1;
    __shared__ float sSo[8][6];
    __shared__ float sHM[4][32];

    float redA, redB;
    edge_pair(o0, i, PJF, PIH, WEH, W2F, edge, eb2, redA, redB);

    const float outA = node_mlp<32>((o0 << 9) | i, redA, h, nw1, nb1, nw2, nb2);
    const float outB = node_mlp<32>(((o0 + 1) << 9) | i, redB, h, nw1, nb1, nw2, nb2);

    const int c = lane & 31;
    if (lane < 32) sHM[wv][c] = outA + outB;

    // Per-frame spatial decoder (2 frames per wave).
    #pragma unroll
    for (int q = 0; q < 2; ++q) {
        const int o = o0 + q;
        const float rh = fmaxf(q ? outB : outA, 0.f);
        float acc = db1[c];
        #pragma unroll
        for (int k = 0; k < 32; ++k)
            acc = fmaf(__shfl(rh, k, 32), dw1[k * 32 + c], acc);
        const float s = fmaxf(acc, 0.f);
        #pragma unroll
        for (int m = 0; m < 6; ++m) {
            float p = s * dw2[c * 6 + m];
            p += __shfl_xor(p, 1); p += __shfl_xor(p, 2); p += __shfl_xor(p, 4);
            p += __shfl_xor(p, 8); p += __shfl_xor(p, 16);
            if (lane == 0) sSo[o][m] = p + db2[m];
        }
    }
    __syncthreads();
    if (wv) return;

    const float hm = (sHM[0][c] + sHM[1][c] + sHM[2][c] + sHM[3][c]) * 0.125f;
    if (lane < 32) out_hmean[i * 32 + c] = hm;
    const float rh = fmaxf(hm, 0.f);
    float acc = vb1[c];
    #pragma unroll
    for (int k = 0; k < 32; ++k)
        acc = fmaf(__shfl(rh, k, 32), vw1[k * 32 + c], acc);
    const float t1 = fmaxf(acc, 0.f);
    float p = t1 * vw2[c];
    p += __shfl_xor(p, 1); p += __shfl_xor(p, 2); p += __shfl_xor(p, 4);
    p += __shfl_xor(p, 8); p += __shfl_xor(p, 16);
    const float coef = p + vb2[0];
    if (lane < 3) {
        const int ii = lane;
        float dx = 0.f, dv = 0.f;
        #pragma unroll
        for (int o = 0; o < 8; ++o) {
            #pragma unroll
            for (int j = 0; j < 3; ++j) {
                float sgn = ((o >> (2 - j)) & 1) ? -1.f : 1.f;
                float f = sgn * FR[3 + ii * 3 + j];
                dx = fmaf(f, sSo[o][j], dx);
                dv = fmaf(f, sSo[o][3 + j], dv);
            }
        }
        dx *= 0.125f; dv *= 0.125f;
        const float vout = v[i * 3 + ii] + dv;
        out_v[i * 3 + ii] = vout;
        out_x[i * 3 + ii] = x[i * 3 + ii] + vout * coef + dx;
    }
}

// ---------------------------------------------------------------------------
extern "C" void kernel_launch(void* const* d_in, const int* in_sizes, int n_in,
                              void* d_out, int out_size, void* d_ws, size_t ws_size,
                              hipStream_t stream) {
    const float* node_feat = (const float*)d_in[0];
    const float* edge      = (const float*)d_in[1];
    const float* x         = (const float*)d_in[2];
    const float* v         = (const float*)d_in[3];
    const float* e0_w1 = (const float*)d_in[4];
    const float* e0_b1 = (const float*)d_in[5];
    const float* e0_w2 = (const float*)d_in[6];
    const float* e0_b2 = (const float*)d_in[7];
    const float* n0_w1 = (const float*)d_in[8];
    const float* n0_b1 = (const float*)d_in[9];
    const float* n0_w2 = (const float*)d_in[10];
    const float* n0_b2 = (const float*)d_in[11];
    const float* e1_w1 = (const float*)d_in[12];
    const float* e1_b1 = (const float*)d_in[13];
    const float* e1_w2 = (const float*)d_in[14];
    const float* e1_b2 = (const float*)d_in[15];
    const float* n1_w1 = (const float*)d_in[16];
    const float* n1_b1 = (const float*)d_in[17];
    const float* n1_w2 = (const float*)d_in[18];
    const float* n1_b2 = (const float*)d_in[19];
    const float* dec_w1 = (const float*)d_in[20];
    const float* dec_b1 = (const float*)d_in[21];
    const float* dec_w2 = (const float*)d_in[22];
    const float* dec_b2 = (const float*)d_in[23];
    const float* vc_w1 = (const float*)d_in[24];
    const float* vc_b1 = (const float*)d_in[25];
    const float* vc_w2 = (const float*)d_in[26];
    const float* vc_b2 = (const float*)d_in[27];

    char* wsb = (char*)d_ws;
    float* out = (float*)d_out;

    float*    FR   = (float*)wsb;                            // 12 f32
    float*    H0   = (float*)(wsb + 256);                    // 57344 f32
    float*    HA   = (float*)(wsb + 256 + 229376);           // 131072 f32
    char*     p    = wsb + 256 + 229376 + 524288 + 524288;
    _Float16* PJF0 = (_Float16*)p;            p += 262144;   // 131072 f16
    _Float16* PIH0 = (_Float16*)p;            p += 262144;
    _Float16* PJF1 = (_Float16*)p;            p += 262144;
    _Float16* PIH1 = (_Float16*)p;            p += 262144;
    _Float16* WEH0 = (_Float16*)p;            p += 256;
    _Float16* WEH1 = (_Float16*)p;            p += 256;
    _Float16* W2F0 = (_Float16*)p;            p += 2048;
    _Float16* W2F1 = (_Float16*)p;            p += 2048;

    // K1: frame + h0 + layer-0 pre + weight convert + edge passthrough
    pre0_kernel<<<512, 256, 0, stream>>>(x, v, node_feat,
                                         e0_w1, e0_b1, e0_w2, e1_w1, e1_w2,
                                         edge, FR, H0, PJF0, PIH0,
                                         WEH0, WEH1, W2F0, W2F1, out + 16384);
    // K2a: layer 0 (D=14), block = node, fuses layer-1 pre-projection
    edgeA_kernel<<<512, 256, 0, stream>>>(
        PJF0, PIH0, WEH0, W2F0, edge, H0, e0_b2, n0_w1, n0_b1, n0_w2, n0_b2,
        HA, e1_w1, e1_b1, PJF1, PIH1);
    // K2b: layer 1 (D=32) + decoder + h_mean + coef + invert_frame
    edgeB_kernel<<<512, 256, 0, stream>>>(
        PJF1, PIH1, WEH1, W2F1, edge, HA, e1_b2, n1_w1, n1_b1, n1_w2, n1_b2,
        dec_w1, dec_b1, dec_w2, dec_b2, x, v, FR,
        vc_w1, vc_b1, vc_w2, vc_b2,
        out, out + 278528, out + 280064);
}